// Round 14
// baseline (68.478 us; speedup 1.0000x reference)
//
#include <hip/hip_runtime.h>

typedef __attribute__((ext_vector_type(8))) __bf16 bf16x8;
typedef __attribute__((ext_vector_type(4))) float f32x4;
typedef __attribute__((ext_vector_type(16))) float f32x16;
typedef __attribute__((ext_vector_type(4))) int i32x4;

constexpr int Bn = 8192, Nn = 256, M1n = 128, M2n = 64, Mn = 192, ITERS = 30;
constexpr float TAUc = 0.05f, SIGc = 0.05f;

__device__ __forceinline__ ushort f2bf(float f) {
  unsigned u = __builtin_bit_cast(unsigned, f);
  u = (u + 0x7FFFu + ((u >> 16) & 1u)) >> 16;
  return (ushort)u;
}

// packed f32->bf16 (RNE), 2 values per instruction
__device__ __forceinline__ unsigned cvtpk(float lo, float hi) {
  unsigned r;
  asm("v_cvt_pk_bf16_f32 %0, %1, %2" : "=v"(r) : "v"(lo), "v"(hi));
  return r;
}

// Pin a fragment into AGPRs: volatile asm result, cannot be rematerialized.
__device__ __forceinline__ void pina(i32x4& v) { asm volatile("" : "+a"(v)); }

// 32x32x16 MFMA, swapped operands: A-op = pinned A-matrix fragment
// (row=lane&31, k=(lane>>5)*8+j), B-op = LDS-streamed x/y fragment
// (col=batch=lane&31, same k). C/D: col=lane&31(batch),
// row=(reg&3)+8*(reg>>2)+4*(lane>>5)  [m74/m101-verified].
__device__ __forceinline__ f32x16 mfma32(i32x4 afrag, bf16x8 b, f32x16 acc) {
  return __builtin_amdgcn_mfma_f32_32x32x16_bf16(
      __builtin_bit_cast(bf16x8, afrag), b, acc, 0, 0, 0);
}

// Build bf16 copies of A = [A1;A2] in both orientations:
// Arm[m][n] (192x256 row-major), AT[n][m] (256x192 row-major).
__global__ void prep_kernel(const float* __restrict__ A1, const float* __restrict__ A2,
                            ushort* __restrict__ Arm, ushort* __restrict__ AT) {
  int i = blockIdx.x * 256 + threadIdx.x;
  if (i >= Mn * Nn) return;
  int m = i / Nn, n = i % Nn;
  float v = (m < M1n) ? A1[m * Nn + n] : A2[(m - M1n) * Nn + n];
  ushort b = f2bf(v);
  Arm[m * Nn + n] = b;
  AT[n * Mn + m] = b;
}

// 8 waves, ONE 32-row band per block. grid = 256 = 1 block/CU, 2 waves/SIMD.
// 32x32x16 MFMA: G1: waves 0-5 -> m-tile w (16 ks); tiles 0-3 relu, 4-5 linear.
//                G3: all waves -> n-tile w (12 ks).
// AGPR frags: G1 waves 16+12=28 (112 regs), others 12 (48). Streamed-operand
// LDS traffic halves vs 16x16 (32 KFLOP per 1KB wave-read).
__global__ __launch_bounds__(512, 2) void pdhg_kernel(
    const float* __restrict__ x0, const float* __restrict__ y10,
    const float* __restrict__ y20, const float* __restrict__ z,
    const float* __restrict__ c, const ushort* __restrict__ Arm,
    const ushort* __restrict__ AT, float* __restrict__ out) {
  __shared__ __align__(16) ushort xb_lds[32][264];  // xbar band (bf16), padded
  __shared__ __align__(16) ushort y_lds[32][200];   // y band (bf16), padded

  const int lane = threadIdx.x & 63;
  const int w = threadIdx.x >> 6;     // wave 0..7
  const int bcol = lane & 31;         // batch row within band / A-matrix row
  const int h = lane >> 5;            // k-half (8 bf16 each)
  const int row0 = blockIdx.x * 32;   // this block's 32-row band
  const int rB = row0 + bcol;         // this lane's global batch row

  const int N0 = 32 * w;              // G3 n-tile base
  const bool g1w = (w < 6);           // waves 0..5 own G1 m-tile w
  const int M0 = 32 * w;              // G1 m-tile base (g1w only)
  const bool relu = (w < 4);          // m 0..127 = y1 (relu); 128..191 = y2

  float x[16], cv[16], ys[16], zs[16];

  // ---- init x, c (C/D row layout groups: 4 consecutive rows per g2)
#pragma unroll
  for (int g2 = 0; g2 < 4; ++g2) {
    const int n0 = N0 + 8 * g2 + 4 * h;
    f32x4 cvv = *reinterpret_cast<const f32x4*>(&c[n0]);
    f32x4 xv = *reinterpret_cast<const f32x4*>(&x0[rB * Nn + n0]);
#pragma unroll
    for (int j = 0; j < 4; ++j) { cv[4 * g2 + j] = cvv[j]; x[4 * g2 + j] = xv[j]; }
    uint2 p = make_uint2(cvtpk(xv[0], xv[1]), cvtpk(xv[2], xv[3]));
    *reinterpret_cast<uint2*>(&xb_lds[bcol][n0]) = p;
  }
  // ---- init y, sigma*z (G1 waves only)
  if (g1w) {
#pragma unroll
    for (int g2 = 0; g2 < 4; ++g2) {
      const int m0 = M0 + 8 * g2 + 4 * h;
      f32x4 zv = *reinterpret_cast<const f32x4*>(&z[rB * Mn + m0]);
      f32x4 yv = relu ? *reinterpret_cast<const f32x4*>(&y10[rB * M1n + m0])
                      : *reinterpret_cast<const f32x4*>(&y20[rB * M2n + (m0 - M1n)]);
#pragma unroll
      for (int j = 0; j < 4; ++j) { zs[4 * g2 + j] = SIGc * zv[j]; ys[4 * g2 + j] = yv[j]; }
    }
  }

  // ---- preload loop-invariant A fragments into AGPRs
  i32x4 armF[16], atF[12];
  if (g1w) {
#pragma unroll
    for (int ks = 0; ks < 16; ++ks) {
      armF[ks] = *reinterpret_cast<const i32x4*>(&Arm[(M0 + bcol) * Nn + ks * 16 + h * 8]);
      pina(armF[ks]);
    }
  }
#pragma unroll
  for (int ks = 0; ks < 12; ++ks) {
    atF[ks] = *reinterpret_cast<const i32x4*>(&AT[(N0 + bcol) * Mn + ks * 16 + h * 8]);
    pina(atF[ks]);
  }

  __syncthreads();

  for (int it = 0; it < ITERS; ++it) {
    // ---- GEMM-1: S = A x̄^T  (waves 0-5; 16 ks; fx streamed from LDS)
    if (g1w) {
      f32x16 acc;
#pragma unroll
      for (int i = 0; i < 16; ++i) acc[i] = 0.f;
#pragma unroll
      for (int ks = 0; ks < 16; ++ks) {
        bf16x8 fx = *reinterpret_cast<const bf16x8*>(&xb_lds[bcol][ks * 16 + h * 8]);
        acc = mfma32(armF[ks], fx, acc);
      }
      // y update (f32 reg state)
#pragma unroll
      for (int i = 0; i < 16; ++i) {
        float s = __builtin_fmaf(SIGc, acc[i], ys[i]) - zs[i];
        ys[i] = relu ? fmaxf(s, 0.f) : s;
      }
      // write bf16 Y: 4 x ds_write_b64 (4 consecutive m-rows each)
#pragma unroll
      for (int g2 = 0; g2 < 4; ++g2) {
        uint2 p = make_uint2(cvtpk(ys[4 * g2], ys[4 * g2 + 1]),
                             cvtpk(ys[4 * g2 + 2], ys[4 * g2 + 3]));
        *reinterpret_cast<uint2*>(&y_lds[bcol][M0 + 8 * g2 + 4 * h]) = p;
      }
    }
    __syncthreads();

    // ---- GEMM-3: G = A^T y^T  (all waves; 12 ks; fy streamed from LDS)
    f32x16 acc2;
#pragma unroll
    for (int i = 0; i < 16; ++i) acc2[i] = 0.f;
#pragma unroll
    for (int ks = 0; ks < 12; ++ks) {
      bf16x8 fy = *reinterpret_cast<const bf16x8*>(&y_lds[bcol][ks * 16 + h * 8]);
      acc2 = mfma32(atF[ks], fy, acc2);
    }

    // ---- x update; write bf16 xbar: 4 x ds_write_b64
    const bool notlast = (it != ITERS - 1);
    float xb[16];
#pragma unroll
    for (int i = 0; i < 16; ++i) {
      float grad = cv[i] + acc2[i];
      float xn = fmaxf(__builtin_fmaf(-TAUc, grad, x[i]), 0.f);
      xb[i] = 2.f * xn - x[i];  // theta = 1
      x[i] = xn;
    }
    if (notlast) {
#pragma unroll
      for (int g2 = 0; g2 < 4; ++g2) {
        uint2 p = make_uint2(cvtpk(xb[4 * g2], xb[4 * g2 + 1]),
                             cvtpk(xb[4 * g2 + 2], xb[4 * g2 + 3]));
        *reinterpret_cast<uint2*>(&xb_lds[bcol][N0 + 8 * g2 + 4 * h]) = p;
      }
      __syncthreads();
    }
  }

  // ---- store outputs (dwordx4): x (Bx256), y1 (Bx128), y2 (Bx64)
  float* ox = out;
  float* oy1 = out + Bn * Nn;
  float* oy2 = oy1 + Bn * M1n;
#pragma unroll
  for (int g2 = 0; g2 < 4; ++g2) {
    const int n0 = N0 + 8 * g2 + 4 * h;
    f32x4 v;
#pragma unroll
    for (int j = 0; j < 4; ++j) v[j] = x[4 * g2 + j];
    *reinterpret_cast<f32x4*>(&ox[rB * Nn + n0]) = v;
  }
  if (g1w) {
#pragma unroll
    for (int g2 = 0; g2 < 4; ++g2) {
      const int m0 = M0 + 8 * g2 + 4 * h;
      f32x4 v;
#pragma unroll
      for (int j = 0; j < 4; ++j) v[j] = ys[4 * g2 + j];
      if (relu) *reinterpret_cast<f32x4*>(&oy1[rB * M1n + m0]) = v;
      else      *reinterpret_cast<f32x4*>(&oy2[rB * M2n + (m0 - M1n)]) = v;
    }
  }
}

extern "C" void kernel_launch(void* const* d_in, const int* in_sizes, int n_in,
                              void* d_out, int out_size, void* d_ws, size_t ws_size,
                              hipStream_t stream) {
  const float* x0  = (const float*)d_in[0];
  const float* y10 = (const float*)d_in[1];
  const float* y20 = (const float*)d_in[2];
  const float* z   = (const float*)d_in[3];
  const float* c   = (const float*)d_in[4];
  const float* A1  = (const float*)d_in[5];
  const float* A2  = (const float*)d_in[6];

  ushort* Arm = (ushort*)d_ws;          // 192*256 bf16
  ushort* AT  = Arm + Mn * Nn;          // 256*192 bf16

  prep_kernel<<<(Mn * Nn + 255) / 256, 256, 0, stream>>>(A1, A2, Arm, AT);
  pdhg_kernel<<<Bn / 32, 512, 0, stream>>>(x0, y10, y20, z, c, Arm, AT, (float*)d_out);
}

// Round 15
// 67.096 us; speedup vs baseline: 1.0206x; 1.0206x over previous
//
#include <hip/hip_runtime.h>

typedef __attribute__((ext_vector_type(8))) __bf16 bf16x8;
typedef __attribute__((ext_vector_type(4))) float f32x4;
typedef __attribute__((ext_vector_type(4))) int i32x4;

constexpr int Bn = 8192, Nn = 256, M1n = 128, M2n = 64, Mn = 192, ITERS = 30;
constexpr float TAUc = 0.05f, SIGc = 0.05f;

__device__ __forceinline__ ushort f2bf(float f) {
  unsigned u = __builtin_bit_cast(unsigned, f);
  u = (u + 0x7FFFu + ((u >> 16) & 1u)) >> 16;
  return (ushort)u;
}

// packed f32->bf16 (RNE), 2 values per instruction
__device__ __forceinline__ unsigned cvtpk(float lo, float hi) {
  unsigned r;
  asm("v_cvt_pk_bf16_f32 %0, %1, %2" : "=v"(r) : "v"(lo), "v"(hi));
  return r;
}

// Pin a fragment into AGPRs: volatile asm result, cannot be rematerialized.
__device__ __forceinline__ void pina(i32x4& v) { asm volatile("" : "+a"(v)); }

// SWAPPED builtin MFMA: A-operand = pinned A-matrix fragment, B-operand = the
// LDS-streamed x/y fragment. Lane(fr,kg) reg g = D[m/n = tile*16+kg*4+g][batch=fr].
__device__ __forceinline__ f32x4 mfma_swp(i32x4 afrag, bf16x8 b, f32x4 acc) {
  return __builtin_amdgcn_mfma_f32_16x16x32_bf16(
      __builtin_bit_cast(bf16x8, afrag), b, acc, 0, 0, 0);
}

// T2 XOR-swizzle: permute 16B slots within each row by (row&7). Rows are
// 512B (power-of-2) so the XOR is bijective in-row; applied identically on
// write and read (both-sides-or-neither). Preserves 8B/16B alignment.
__device__ __forceinline__ char* swz(void* rowbase, int row, int byteoff) {
  return (char*)rowbase + (byteoff ^ ((row & 7) << 4));
}

// Build bf16 copies of A = [A1;A2] in both orientations:
// Arm[m][n] (192x256 row-major), AT[n][m] (256x192 row-major).
__global__ void prep_kernel(const float* __restrict__ A1, const float* __restrict__ A2,
                            ushort* __restrict__ Arm, ushort* __restrict__ AT) {
  int i = blockIdx.x * 256 + threadIdx.x;
  if (i >= Mn * Nn) return;
  int m = i / Nn, n = i % Nn;
  float v = (m < M1n) ? A1[m * Nn + n] : A2[(m - M1n) * Nn + n];
  ushort b = f2bf(v);
  Arm[m * Nn + n] = b;
  AT[n * Mn + m] = b;
}

// 8 waves, 32 rows (2 bands). grid = 256 = 1 block/CU, 2 waves/SIMD.
// GEMM-1 (band-split): wave w -> band w&1, m-tiles {3*(w>>1)+0..2} (8 fx reads).
// GEMM-3: n-tiles {2w,2w+1} x both bands (12 fy reads; atF reused across bands).
// 36 A-frags pinned in AGPRs (144) = the proven no-spill budget at occ 2.
// r15 delta vs r8: 512B LDS rows + XOR-swizzle (T2) to kill bank conflicts.
__global__ __launch_bounds__(512, 2) void pdhg_kernel(
    const float* __restrict__ x0, const float* __restrict__ y10,
    const float* __restrict__ y20, const float* __restrict__ z,
    const float* __restrict__ c, const ushort* __restrict__ Arm,
    const ushort* __restrict__ AT, float* __restrict__ out) {
  __shared__ __align__(16) ushort xb_lds[2][16][256];  // xbar bands, 512B rows
  __shared__ __align__(16) ushort y_lds[2][16][256];   // y bands, 512B rows

  const int lane = threadIdx.x & 63;
  const int w = threadIdx.x >> 6;     // wave 0..7
  const int fr = lane & 15;           // batch row within band (output col)
  const int kg = lane >> 4;           // k-group / output row-quad
  const int row0 = blockIdx.x * 32;   // 32-row super-band

  const int b1 = w & 1;               // GEMM-1 band
  const int mg = w >> 1;              // GEMM-1 m-tile group: tiles 3mg..3mg+2
  const int rG1 = row0 + 16 * b1 + fr;  // GEMM-1 batch row of this lane

  float x[2][2][4];     // [n-tile t][band b][g]
  float cv[2][4];
  float ys[3][4], zs[3][4];

  // ---- init x state (dwordx4) + initial xbar into LDS (b64, swizzled)
#pragma unroll
  for (int t = 0; t < 2; ++t) {
    const int n0 = (2 * w + t) * 16 + kg * 4;
    *reinterpret_cast<f32x4*>(cv[t]) = *reinterpret_cast<const f32x4*>(&c[n0]);
#pragma unroll
    for (int b = 0; b < 2; ++b) {
      f32x4 v = *reinterpret_cast<const f32x4*>(&x0[(row0 + 16 * b + fr) * Nn + n0]);
#pragma unroll
      for (int g = 0; g < 4; ++g) x[t][b][g] = v[g];
      uint2 p = make_uint2(cvtpk(v[0], v[1]), cvtpk(v[2], v[3]));
      *reinterpret_cast<uint2*>(swz(&xb_lds[b][fr][0], fr, n0 * 2)) = p;
    }
  }
  // ---- init y, sigma*z state (dwordx4; band b1 only)
#pragma unroll
  for (int i = 0; i < 3; ++i) {
    const int mt = 3 * mg + i;
    const int m0 = mt * 16 + kg * 4;
    f32x4 zv = *reinterpret_cast<const f32x4*>(&z[rG1 * Mn + m0]);
    f32x4 yv = (mt < 8) ? *reinterpret_cast<const f32x4*>(&y10[rG1 * M1n + m0])
                        : *reinterpret_cast<const f32x4*>(&y20[rG1 * M2n + (m0 - M1n)]);
#pragma unroll
    for (int g = 0; g < 4; ++g) { zs[i][g] = SIGc * zv[g]; ys[i][g] = yv[g]; }
  }

  // ---- preload loop-invariant A fragments into AGPRs (36 frags = 144 AGPR)
  i32x4 armF[3][8], atF[2][6];
#pragma unroll
  for (int i = 0; i < 3; ++i) {
    const int m = (3 * mg + i) * 16 + fr;
#pragma unroll
    for (int kf = 0; kf < 8; ++kf) {
      armF[i][kf] = *reinterpret_cast<const i32x4*>(&Arm[m * Nn + kf * 32 + kg * 8]);
      pina(armF[i][kf]);
    }
  }
#pragma unroll
  for (int t = 0; t < 2; ++t) {
    const int n = (2 * w + t) * 16 + fr;
#pragma unroll
    for (int kf = 0; kf < 6; ++kf) {
      atF[t][kf] = *reinterpret_cast<const i32x4*>(&AT[n * Mn + kf * 32 + kg * 8]);
      pina(atF[t][kf]);
    }
  }

  __syncthreads();

  for (int it = 0; it < ITERS; ++it) {
    // ---- GEMM-1: band b1 only; fx streamed (8 swizzled reads), 3 chains
    f32x4 a0 = {0.f, 0.f, 0.f, 0.f}, a1 = a0, a2 = a0;
#pragma unroll
    for (int kf = 0; kf < 8; ++kf) {
      bf16x8 fx = *reinterpret_cast<const bf16x8*>(
          swz(&xb_lds[b1][fr][0], fr, kf * 64 + kg * 16));
      a0 = mfma_swp(armF[0][kf], fx, a0);
      a1 = mfma_swp(armF[1][kf], fx, a1);
      a2 = mfma_swp(armF[2][kf], fx, a2);
    }

    // ---- y update; write bf16 Y (one swizzled ds_write_b64 per tile)
#pragma unroll
    for (int i = 0; i < 3; ++i) {
      const int mt = 3 * mg + i;
      const int m0 = mt * 16 + kg * 4;
      const f32x4 ai = (i == 0) ? a0 : (i == 1) ? a1 : a2;
      const bool relu = (mt < 8);
#pragma unroll
      for (int g = 0; g < 4; ++g) {
        float s = __builtin_fmaf(SIGc, ai[g], ys[i][g]) - zs[i][g];
        ys[i][g] = relu ? fmaxf(s, 0.f) : s;
      }
      uint2 p = make_uint2(cvtpk(ys[i][0], ys[i][1]), cvtpk(ys[i][2], ys[i][3]));
      *reinterpret_cast<uint2*>(swz(&y_lds[b1][fr][0], fr, m0 * 2)) = p;
    }
    __syncthreads();

    // ---- GEMM-3: both bands, 2 n-tiles; fy streamed (12 swizzled reads)
    f32x4 q00 = {0.f, 0.f, 0.f, 0.f}, q01 = q00, q10 = q00, q11 = q00;  // q{band}{t}
#pragma unroll
    for (int kf = 0; kf < 6; ++kf) {
      bf16x8 g0 = *reinterpret_cast<const bf16x8*>(
          swz(&y_lds[0][fr][0], fr, kf * 64 + kg * 16));
      bf16x8 g1 = *reinterpret_cast<const bf16x8*>(
          swz(&y_lds[1][fr][0], fr, kf * 64 + kg * 16));
      q00 = mfma_swp(atF[0][kf], g0, q00);
      q01 = mfma_swp(atF[1][kf], g0, q01);
      q10 = mfma_swp(atF[0][kf], g1, q10);
      q11 = mfma_swp(atF[1][kf], g1, q11);
    }

    // ---- x update; write bf16 xbar (one swizzled ds_write_b64 per tile x band)
    const bool notlast = (it != ITERS - 1);
#pragma unroll
    for (int t = 0; t < 2; ++t) {
      const int n0 = (2 * w + t) * 16 + kg * 4;
#pragma unroll
      for (int b = 0; b < 2; ++b) {
        const f32x4 qt = (t == 0) ? (b == 0 ? q00 : q10) : (b == 0 ? q01 : q11);
        float xb[4];
#pragma unroll
        for (int g = 0; g < 4; ++g) {
          float grad = cv[t][g] + qt[g];
          float xn = fmaxf(__builtin_fmaf(-TAUc, grad, x[t][b][g]), 0.f);
          xb[g] = 2.f * xn - x[t][b][g];  // theta = 1
          x[t][b][g] = xn;
        }
        if (notlast) {
          uint2 p = make_uint2(cvtpk(xb[0], xb[1]), cvtpk(xb[2], xb[3]));
          *reinterpret_cast<uint2*>(swz(&xb_lds[b][fr][0], fr, n0 * 2)) = p;
        }
      }
    }
    if (notlast) __syncthreads();
  }

  // ---- store outputs (all dwordx4): x (Bx256), y1 (Bx128), y2 (Bx64)
  float* ox = out;
  float* oy1 = out + Bn * Nn;
  float* oy2 = oy1 + Bn * M1n;
#pragma unroll
  for (int t = 0; t < 2; ++t) {
    const int n0 = (2 * w + t) * 16 + kg * 4;
#pragma unroll
    for (int b = 0; b < 2; ++b) {
      f32x4 v;
#pragma unroll
      for (int g = 0; g < 4; ++g) v[g] = x[t][b][g];
      *reinterpret_cast<f32x4*>(&ox[(row0 + 16 * b + fr) * Nn + n0]) = v;
    }
  }
#pragma unroll
  for (int i = 0; i < 3; ++i) {
    const int mt = 3 * mg + i;
    const int m0 = mt * 16 + kg * 4;
    f32x4 v;
#pragma unroll
    for (int g = 0; g < 4; ++g) v[g] = ys[i][g];
    if (mt < 8) *reinterpret_cast<f32x4*>(&oy1[rG1 * M1n + m0]) = v;
    else        *reinterpret_cast<f32x4*>(&oy2[rG1 * M2n + (m0 - M1n)]) = v;
  }
}

extern "C" void kernel_launch(void* const* d_in, const int* in_sizes, int n_in,
                              void* d_out, int out_size, void* d_ws, size_t ws_size,
                              hipStream_t stream) {
  const float* x0  = (const float*)d_in[0];
  const float* y10 = (const float*)d_in[1];
  const float* y20 = (const float*)d_in[2];
  const float* z   = (const float*)d_in[3];
  const float* c   = (const float*)d_in[4];
  const float* A1  = (const float*)d_in[5];
  const float* A2  = (const float*)d_in[6];

  ushort* Arm = (ushort*)d_ws;          // 192*256 bf16
  ushort* AT  = Arm + Mn * Nn;          // 256*192 bf16

  prep_kernel<<<(Mn * Nn + 255) / 256, 256, 0, stream>>>(A1, A2, Arm, AT);
  pdhg_kernel<<<Bn / 32, 512, 0, stream>>>(x0, y10, y20, z, c, Arm, AT, (float*)d_out);
}